// Round 5
// baseline (760.934 us; speedup 1.0000x reference)
//
#include <hip/hip_runtime.h>
#include <cstdint>
#include <cstddef>

typedef unsigned int  uint_t;
typedef unsigned short ushort_t;

// ---- shapes (fixed for this problem) ----
constexpr int B_  = 64;
constexpr int S_  = 128;
constexpr int D_  = 100;   // triple embedding dim
constexpr int E_  = 300;   // word embedding dim
constexpr int H_  = 256;   // hidden
constexpr int KIN = 512;   // LSTM input 500 padded to 512 for MFMA K
constexpr int NG  = 1024;  // 4*H gates
constexpr int M_  = B_ * S_;  // 8192

// K3 weight split: per gate row, each thread owns 64 f16x2 words (half of K);
// RW in VGPRs/AGPRs, LW in LDS.
constexpr int RW = 48;
constexpr int LW = 16;   // 4 chunks of 4 words

// ---- workspace layout (bytes) ----
constexpr size_t OFF_WT   = 0;                                  // W_ent^T packed f16x2 [100 kp][100 d] (40000 B)
constexpr size_t OFF_FLAG = 40000;                              // int: 1 if inputs are fp32, 0 if bf16
constexpr size_t OFF_WIH  = 40960;                              // W_ih padded bf16 [1024][512]
constexpr size_t OFF_WHH  = OFF_WIH + (size_t)NG * KIN * 2;     // W_hh as f16x2, [128][1024] u32
constexpr size_t OFF_TIN  = OFF_WHH + (size_t)128 * NG * 4;     // t_in bf16 [8192][512]
constexpr size_t OFF_XG   = OFF_TIN + (size_t)M_ * KIN * 2;     // xg f32 [8192][1024]
constexpr size_t OFF_HOUT = OFF_XG + (size_t)M_ * NG * 4;       // h f32 [8192][256]
// total ~50 MB

// ---- helpers ----
__device__ __forceinline__ float b2f(ushort_t u) {
  union { uint_t u; float f; } v; v.u = ((uint_t)u) << 16; return v.f;
}
__device__ __forceinline__ float blo(uint_t u) {
  union { uint_t u; float f; } v; v.u = u << 16; return v.f;
}
__device__ __forceinline__ float bhi(uint_t u) {
  union { uint_t u; float f; } v; v.u = u & 0xffff0000u; return v.f;
}
__device__ __forceinline__ ushort_t f2b(float f) {  // RNE float->bf16
  union { float f; uint_t u; } v; v.f = f;
  uint_t r = (v.u + 0x7fffu + ((v.u >> 16) & 1u)) >> 16;
  return (ushort_t)r;
}
__device__ __forceinline__ ushort_t f16bits(float f) {
  _Float16 h = (_Float16)f;
  union { _Float16 h; ushort_t u; } v; v.h = h; return v.u;
}
__device__ __forceinline__ uint_t pk16(float a, float b) {
  return (uint_t)f16bits(a) | ((uint_t)f16bits(b) << 16);
}
__device__ __forceinline__ float fast_tanh(float x) {
  float e = __expf(2.f * x);
  return 1.f - 2.f / (e + 1.f);
}
__device__ __forceinline__ float sigm(float x) {
  return 1.f / (1.f + __expf(-x));
}
// dtype-flexible load of an external "float" tensor
__device__ __forceinline__ float ldv(const void* p, size_t i, int f32) {
  return f32 ? ((const float*)p)[i] : b2f(((const ushort_t*)p)[i]);
}

#if defined(__has_builtin)
#if __has_builtin(__builtin_amdgcn_fdot2)
#define HAVE_FDOT2 1
#endif
#endif

typedef _Float16 half2v __attribute__((ext_vector_type(2)));

__device__ __forceinline__ float dot2(uint_t w, uint_t h, float acc) {
#ifdef HAVE_FDOT2
  union { uint_t u; half2v v; } a, b; a.u = w; b.u = h;
  return __builtin_amdgcn_fdot2(a.v, b.v, acc, false);
#else
  union { uint_t u; _Float16 h[2]; } a, b; a.u = w; b.u = h;
  acc += (float)a.h[0] * (float)b.h[0];
  acc += (float)a.h[1] * (float)b.h[1];
  return acc;
#endif
}

// =====================================================================
// K_detect: decide whether external float tensors are fp32 or bf16.
// =====================================================================
__global__ __launch_bounds__(64) void k_detect(const uint_t* __restrict__ emb_w,
                                               char* __restrict__ ws)
{
  int tid = threadIdx.x;
  int hits = 0;
  for (int i = 0; i < 8; ++i) {
    uint_t w = emb_w[i * 64 + tid];
    uint_t e = (w >> 7) & 0xffu;   // exponent field of lo-ushort-as-bf16
    hits += (e >= 140) ? 1 : 0;
  }
  for (int off = 32; off > 0; off >>= 1) hits += __shfl_down(hits, off);
  if (tid == 0) *(int*)(ws + OFF_FLAG) = (hits >= 32) ? 1 : 0;
}

// =====================================================================
// K0: weight prep. Wt = W_ent^T packed f16x2 (K-pairs); W_ih padded
// K 500->512 (bf16); W_hh -> f16x2 packed, transposed to [kpair][row].
// =====================================================================
__global__ __launch_bounds__(256) void k0_prep(
    const void* __restrict__ W_ent, const void* __restrict__ W_ih,
    const void* __restrict__ W_hh, char* __restrict__ ws)
{
  const int f32 = *(const int*)(ws + OFF_FLAG);
  int id = blockIdx.x * 256 + threadIdx.x;
  uint_t*   Wt = (uint_t*)(ws + OFF_WT);
  ushort_t* Wp = (ushort_t*)(ws + OFF_WIH);
  uint_t*   WT = (uint_t*)(ws + OFF_WHH);
  if (id < 10000) {
    // Wt[kp*100+d] = pack(f16(W_ent[d][2kp]), f16(W_ent[d][2kp+1]))
    int kp = id / 100, d = id % 100;
    float a = ldv(W_ent, (size_t)d * 200 + 2 * kp,     f32);
    float b = ldv(W_ent, (size_t)d * 200 + 2 * kp + 1, f32);
    Wt[id] = pk16(a, b);
  } else if (id >= 20000 && id < 20000 + NG * KIN) {
    int i = id - 20000;
    int n = i >> 9, k = i & 511;
    Wp[i] = (k < 500) ? f2b(ldv(W_ih, (size_t)n * 500 + k, f32)) : (ushort_t)0;
  } else if (id >= 20000 + NG * KIN && id < 20000 + NG * KIN + 128 * NG) {
    int i = id - 20000 - NG * KIN;
    int kk = i >> 10, j = i & 1023;
    ushort_t lo = f16bits(ldv(W_hh, (size_t)j * 256 + 2 * kk,     f32));
    ushort_t hi = f16bits(ldv(W_hh, (size_t)j * 256 + 2 * kk + 1, f32));
    WT[kk * 1024 + j] = (uint_t)lo | ((uint_t)hi << 16);
  }
}

// =====================================================================
// K1: triple graph attention; writes t_in bf16 [m][512].
// 4 tokens per block, 512 threads (token slot j = tid>>7, local
// lt = tid&127). Wl2 (40 KB) staged ONCE per block; LDS 72.8 KB ->
// 2 blocks/CU x 8 waves = 4 waves/SIMD. Packed f16x2 dot2 hot loop.
// =====================================================================
__global__ __launch_bounds__(512) void k1_graph(
    const int* __restrict__ inputs, const int* __restrict__ triples,
    const int* __restrict__ id2, const void* __restrict__ emb,
    const void* __restrict__ ent, const void* __restrict__ rel,
    char* __restrict__ ws)
{
  __shared__ __align__(16) uint_t Wl2[10000];    // packed f16x2 [kp][d], 40000 B
  __shared__ uint_t htp[4][10][100];             // packed f16x2 per token
  __shared__ float er_l[4][10][100];
  __shared__ float e_l[4][10];
  __shared__ float alpha_l[4][10];
  __shared__ int   trip_l[4][30];
  __shared__ int   vflag[4];

  const int tid = threadIdx.x;
  const int j   = tid >> 7;        // token slot 0..3
  const int lt  = tid & 127;       // local tid within token group
  const int m   = blockIdx.x * 4 + j;  // b*128+s
  const int f32 = *(const int*)(ws + OFF_FLAG);
  ushort_t* tin = (ushort_t*)(ws + OFF_TIN);

  if (lt < 30) trip_l[j][lt] = triples[(size_t)m * 30 + lt];
  if (lt == 0) vflag[j] = 0;
  if (lt < 10) e_l[j][lt] = 0.f;
  __syncthreads();
  if (lt < 10 && id2[(size_t)m * 10 + lt] != -1) atomicOr(&vflag[j], 1);

  {
    const uint4* src = (const uint4*)(ws + OFF_WT);
    uint4* dst = (uint4*)Wl2;
    for (int i = tid; i < 2500; i += 512) dst[i] = src[i];
  }
  // gather ht rows, pack to f16x2 pairs
  for (int i = lt; i < 1000; i += 128) {
    int t = i / 100, kp = i % 100;
    int row = trip_l[j][t * 3 + (kp < 50 ? 0 : 1)];
    int off = (kp < 50) ? 2 * kp : 2 * (kp - 50);
    float x0, x1;
    if (f32) {
      float2 v = *(const float2*)((const float*)ent + (size_t)row * 100 + off);
      x0 = v.x; x1 = v.y;
    } else {
      uint_t u = *(const uint_t*)((const ushort_t*)ent + (size_t)row * 100 + off);
      x0 = blo(u); x1 = bhi(u);
    }
    htp[j][t][kp] = pk16(x0, x1);
  }
  for (int i = lt; i < 1000; i += 128) {
    int t = i / 100, d = i % 100;
    er_l[j][t][d] = ldv(rel, (size_t)trip_l[j][t * 3 + 2] * 100 + d, f32);
  }
  {
    int w = inputs[m];
    for (int c = lt; c < 300; c += 128)
      tin[(size_t)m * KIN + c] = f2b(ldv(emb, (size_t)w * E_ + c, f32));
    if (lt < 12) tin[(size_t)m * KIN + 500 + lt] = 0;
  }
  __syncthreads();

  if (lt < 125) {
    int t2 = lt / 25, d4 = lt % 25;
    int t0 = 2 * t2, t1 = t0 + 1;
    const uint_t* h0p = htp[j][t0];
    const uint_t* h1p = htp[j][t1];
    float a00 = 0, a01 = 0, a02 = 0, a03 = 0;
    float a10 = 0, a11 = 0, a12 = 0, a13 = 0;
    for (int kp = 0; kp < 100; ++kp) {
      uint4 wv = *(const uint4*)&Wl2[kp * 100 + 4 * d4];  // 4 d-columns at this K-pair
      uint_t hp0 = h0p[kp], hp1 = h1p[kp];
      a00 = dot2(wv.x, hp0, a00); a01 = dot2(wv.y, hp0, a01);
      a02 = dot2(wv.z, hp0, a02); a03 = dot2(wv.w, hp0, a03);
      a10 = dot2(wv.x, hp1, a10); a11 = dot2(wv.y, hp1, a11);
      a12 = dot2(wv.z, hp1, a12); a13 = dot2(wv.w, hp1, a13);
    }
    int d = 4 * d4;
    float s0 = fast_tanh(a00) * er_l[j][t0][d]     + fast_tanh(a01) * er_l[j][t0][d + 1]
             + fast_tanh(a02) * er_l[j][t0][d + 2] + fast_tanh(a03) * er_l[j][t0][d + 3];
    float s1 = fast_tanh(a10) * er_l[j][t1][d]     + fast_tanh(a11) * er_l[j][t1][d + 1]
             + fast_tanh(a12) * er_l[j][t1][d + 2] + fast_tanh(a13) * er_l[j][t1][d + 3];
    atomicAdd(&e_l[j][t0], s0);
    atomicAdd(&e_l[j][t1], s1);
  }
  __syncthreads();
  if (lt == 0) {
    float mx = e_l[j][0];
    for (int t = 1; t < 10; ++t) mx = fmaxf(mx, e_l[j][t]);
    float s = 0.f;
    for (int t = 0; t < 10; ++t) { float v = __expf(e_l[j][t] - mx); alpha_l[j][t] = v; s += v; }
    float inv = 1.f / s;
    for (int t = 0; t < 10; ++t) alpha_l[j][t] *= inv;
  }
  __syncthreads();
  for (int kp = lt; kp < 100; kp += 128) {
    float g0 = 0.f, g1 = 0.f;
#pragma unroll
    for (int t = 0; t < 10; ++t) {
      union { uint_t u; _Float16 h[2]; } v; v.u = htp[j][t][kp];
      g0 += alpha_l[j][t] * (float)v.h[0];
      g1 += alpha_l[j][t] * (float)v.h[1];
    }
    if (!vflag[j]) { g0 = 0.f; g1 = 0.f; }
    tin[(size_t)m * KIN + 300 + 2 * kp]     = f2b(g0);
    tin[(size_t)m * KIN + 300 + 2 * kp + 1] = f2b(g1);
  }
}

// =====================================================================
// K2: xg = t_in @ W_ih^T + b.  MFMA 16x16x32 bf16, 128x128 tiles, BK=32.
// =====================================================================
typedef __attribute__((ext_vector_type(8))) short short8;
typedef __attribute__((ext_vector_type(4))) float f32x4;

__global__ __launch_bounds__(256) void k2_xg(
    const void* __restrict__ bl, char* __restrict__ ws)
{
  __shared__ __align__(16) ushort_t As[128 * 32];
  __shared__ __align__(16) ushort_t Bs[128 * 32];
  const ushort_t* A  = (const ushort_t*)(ws + OFF_TIN);
  const ushort_t* Bw = (const ushort_t*)(ws + OFF_WIH);
  float* xg = (float*)(ws + OFF_XG);
  const int f32 = *(const int*)(ws + OFF_FLAG);

  const int tid = threadIdx.x;
  const int m0 = blockIdx.x * 128;
  const int n0 = blockIdx.y * 128;
  const int lane = tid & 63, wv = tid >> 6;
  const int wm = wv & 1, wn = wv >> 1;
  const int g = lane >> 4, r = lane & 15;

  f32x4 acc[4][4] = {};

  for (int ks = 0; ks < 16; ++ks) {
    const int k0 = ks * 32;
    {
      int c0 = tid, c1 = tid + 256;
      uint4 a0 = *(const uint4*)(A  + (size_t)(m0 + (c0 >> 2)) * KIN + k0 + ((c0 & 3) << 3));
      uint4 a1 = *(const uint4*)(A  + (size_t)(m0 + (c1 >> 2)) * KIN + k0 + ((c1 & 3) << 3));
      uint4 b0 = *(const uint4*)(Bw + (size_t)(n0 + (c0 >> 2)) * KIN + k0 + ((c0 & 3) << 3));
      uint4 b1 = *(const uint4*)(Bw + (size_t)(n0 + (c1 >> 2)) * KIN + k0 + ((c1 & 3) << 3));
      ((uint4*)As)[c0] = a0; ((uint4*)As)[c1] = a1;
      ((uint4*)Bs)[c0] = b0; ((uint4*)Bs)[c1] = b1;
    }
    __syncthreads();
    short8 av[4], bv[4];
#pragma unroll
    for (int i = 0; i < 4; ++i)
      av[i] = *(const short8*)&As[(wm * 64 + i * 16 + r) * 32 + g * 8];
#pragma unroll
    for (int j = 0; j < 4; ++j)
      bv[j] = *(const short8*)&Bs[(wn * 64 + j * 16 + r) * 32 + g * 8];
#pragma unroll
    for (int i = 0; i < 4; ++i)
#pragma unroll
      for (int j = 0; j < 4; ++j)
        acc[i][j] = __builtin_amdgcn_mfma_f32_16x16x32_bf16(av[i], bv[j], acc[i][j], 0, 0, 0);
    __syncthreads();
  }
#pragma unroll
  for (int j = 0; j < 4; ++j) {
    int n = n0 + wn * 64 + j * 16 + r;
    float bias = ldv(bl, n, f32);
#pragma unroll
    for (int i = 0; i < 4; ++i) {
      int mrow = m0 + wm * 64 + i * 16 + g * 4;
#pragma unroll
      for (int rr = 0; rr < 4; ++rr)
        xg[(size_t)(mrow + rr) * NG + n] = acc[i][j][rr] + bias;
    }
  }
}

// =====================================================================
// K3: recurrent LSTM, v2: TWO batches per block (32 blocks x 512 thr).
// W_hh is step-invariant and shared -> each weight word read (AGPR or
// LDS) now feeds 2x dot2 work (two independent batch chains), doubling
// arithmetic intensity per LDS byte and filling the latency stalls that
// bounded v1 (4460 cyc/step vs ~1300 pipe bound at 2 waves/SIMD).
// Same thread-pair/unit/K-half decomposition as v1 per batch.
// LDS: 128 KB ldsw + 2 KB hbuf (2 batches x 2 dbuf x 256 f16).
// =====================================================================
__global__ __attribute__((amdgpu_waves_per_eu(2, 2))) __launch_bounds__(512)
void k3_lstm(char* __restrict__ ws)
{
  extern __shared__ __align__(16) char smem[];
  uint4*    ldsw = (uint4*)smem;                          // [16][512] uint4 = 128 KB
  ushort_t* hbuf = (ushort_t*)(smem + 16 * 512 * 16);     // [2 batch][2 dbuf][256] f16

  const int tid  = threadIdx.x;
  const int b0   = blockIdx.x * 2;
  const int b1   = b0 + 1;
  const int u    = tid >> 1;          // hidden unit 0..255
  const int half = tid & 1;           // K-half
  const int kbase = half * 64;        // first f16x2 word of my K-half

  const uint_t* WT = (const uint_t*)(ws + OFF_WHH);  // [kpair][1024]
  const float* xg = (const float*)(ws + OFF_XG);
  float* hout = (float*)(ws + OFF_HOUT);

  const int row0 = u, row1 = u + 256, row2 = u + 512, row3 = u + 768;

  // ---- register-resident weights: 4 rows x RW words
  uint_t w0[RW], w1[RW], w2[RW], w3[RW];
#pragma unroll
  for (int q = 0; q < RW; ++q) {
    w0[q] = WT[(size_t)(kbase + q) * 1024 + row0];
    w1[q] = WT[(size_t)(kbase + q) * 1024 + row1];
    w2[q] = WT[(size_t)(kbase + q) * 1024 + row2];
    w3[q] = WT[(size_t)(kbase + q) * 1024 + row3];
  }
  // ---- LDS-resident weights: chunk c=i*4+p holds words kbase+RW+4p..+3 of row i
  {
    const int rows[4] = { row0, row1, row2, row3 };
#pragma unroll
    for (int i = 0; i < 4; ++i)
#pragma unroll
      for (int p = 0; p < 4; ++p) {
        uint4 v;
        v.x = WT[(size_t)(kbase + RW + 4 * p + 0) * 1024 + rows[i]];
        v.y = WT[(size_t)(kbase + RW + 4 * p + 1) * 1024 + rows[i]];
        v.z = WT[(size_t)(kbase + RW + 4 * p + 2) * 1024 + rows[i]];
        v.w = WT[(size_t)(kbase + RW + 4 * p + 3) * 1024 + rows[i]];
        ldsw[(i * 4 + p) * 512 + tid] = v;
      }
  }
  hbuf[tid] = 0;          // zero batch0 buffers (512 f16)
  hbuf[512 + tid] = 0;    // zero batch1 buffers (512 f16)
  float c0 = 0.f, c1 = 0.f;
  __syncthreads();

  const int bm0 = b0 * S_, bm1 = b1 * S_;
  // prefetch xg for t=0, both batches
  const float* xpa = xg + (size_t)bm0 * NG;
  const float* xpb = xg + (size_t)bm1 * NG;
  float xa0 = xpa[row0], xa1 = xpa[row1], xa2 = xpa[row2], xa3 = xpa[row3];
  float xb0 = xpb[row0], xb1 = xpb[row1], xb2 = xpb[row2], xb3 = xpb[row3];

  for (int t = 0; t < S_; ++t) {
    const int cur = t & 1;
    float x00 = xa0, x01 = xa1, x02 = xa2, x03 = xa3;
    float x10 = xb0, x11 = xb1, x12 = xb2, x13 = xb3;
    if (t + 1 < S_) {   // prefetch next step's gate inputs
      const float* xqa = xg + (size_t)(bm0 + t + 1) * NG;
      const float* xqb = xg + (size_t)(bm1 + t + 1) * NG;
      xa0 = xqa[row0]; xa1 = xqa[row1]; xa2 = xqa[row2]; xa3 = xqa[row3];
      xb0 = xqb[row0]; xb1 = xqb[row1]; xb2 = xqb[row2]; xb3 = xqb[row3];
    }
    const uint_t* hbA = (const uint_t*)(hbuf + cur * 256);        // batch0
    const uint_t* hbB = (const uint_t*)(hbuf + 512 + cur * 256);  // batch1
    float a00 = 0.f, a01 = 0.f, a02 = 0.f, a03 = 0.f;   // batch0 gates
    float a10 = 0.f, a11 = 0.f, a12 = 0.f, a13 = 0.f;   // batch1 gates
    // register part: weights read once, feed both batches
#pragma unroll
    for (int qq = 0; qq < RW / 4; ++qq) {
      uint4 ha = *(const uint4*)&hbA[kbase + 4 * qq];
      uint4 hc = *(const uint4*)&hbB[kbase + 4 * qq];
      a00 = dot2(w0[4 * qq], ha.x, a00); a00 = dot2(w0[4 * qq + 1], ha.y, a00);
      a00 = dot2(w0[4 * qq + 2], ha.z, a00); a00 = dot2(w0[4 * qq + 3], ha.w, a00);
      a10 = dot2(w0[4 * qq], hc.x, a10); a10 = dot2(w0[4 * qq + 1], hc.y, a10);
      a10 = dot2(w0[4 * qq + 2], hc.z, a10); a10 = dot2(w0[4 * qq + 3], hc.w, a10);
      a01 = dot2(w1[4 * qq], ha.x, a01); a01 = dot2(w1[4 * qq + 1], ha.y, a01);
      a01 = dot2(w1[4 * qq + 2], ha.z, a01); a01 = dot2(w1[4 * qq + 3], ha.w, a01);
      a11 = dot2(w1[4 * qq], hc.x, a11); a11 = dot2(w1[4 * qq + 1], hc.y, a11);
      a11 = dot2(w1[4 * qq + 2], hc.z, a11); a11 = dot2(w1[4 * qq + 3], hc.w, a11);
      a02 = dot2(w2[4 * qq], ha.x, a02); a02 = dot2(w2[4 * qq + 1], ha.y, a02);
      a02 = dot2(w2[4 * qq + 2], ha.z, a02); a02 = dot2(w2[4 * qq + 3], ha.w, a02);
      a12 = dot2(w2[4 * qq], hc.x, a12); a12 = dot2(w2[4 * qq + 1], hc.y, a12);
      a12 = dot2(w2[4 * qq + 2], hc.z, a12); a12 = dot2(w2[4 * qq + 3], hc.w, a12);
      a03 = dot2(w3[4 * qq], ha.x, a03); a03 = dot2(w3[4 * qq + 1], ha.y, a03);
      a03 = dot2(w3[4 * qq + 2], ha.z, a03); a03 = dot2(w3[4 * qq + 3], ha.w, a03);
      a13 = dot2(w3[4 * qq], hc.x, a13); a13 = dot2(w3[4 * qq + 1], hc.y, a13);
      a13 = dot2(w3[4 * qq + 2], hc.z, a13); a13 = dot2(w3[4 * qq + 3], hc.w, a13);
    }
    // LDS part: weight uint4s read once, feed both batches
#pragma unroll
    for (int p = 0; p < 4; ++p) {
      uint4 ha = *(const uint4*)&hbA[kbase + RW + 4 * p];
      uint4 hc = *(const uint4*)&hbB[kbase + RW + 4 * p];
      uint4 v0 = ldsw[(0 * 4 + p) * 512 + tid];
      uint4 v1 = ldsw[(1 * 4 + p) * 512 + tid];
      uint4 v2 = ldsw[(2 * 4 + p) * 512 + tid];
      uint4 v3 = ldsw[(3 * 4 + p) * 512 + tid];
      a00 = dot2(v0.x, ha.x, a00); a00 = dot2(v0.y, ha.y, a00);
      a00 = dot2(v0.z, ha.z, a00); a00 = dot2(v0.w, ha.w, a00);
      a10 = dot2(v0.x, hc.x, a10); a10 = dot2(v0.y, hc.y, a10);
      a10 = dot2(v0.z, hc.z, a10); a10 = dot2(v0.w, hc.w, a10);
      a01 = dot2(v1.x, ha.x, a01); a01 = dot2(v1.y, ha.y, a01);
      a01 = dot2(v1.z, ha.z, a01); a01 = dot2(v1.w, ha.w, a01);
      a11 = dot2(v1.x, hc.x, a11); a11 = dot2(v1.y, hc.y, a11);
      a11 = dot2(v1.z, hc.z, a11); a11 = dot2(v1.w, hc.w, a11);
      a02 = dot2(v2.x, ha.x, a02); a02 = dot2(v2.y, ha.y, a02);
      a02 = dot2(v2.z, ha.z, a02); a02 = dot2(v2.w, ha.w, a02);
      a12 = dot2(v2.x, hc.x, a12); a12 = dot2(v2.y, hc.y, a12);
      a12 = dot2(v2.z, hc.z, a12); a12 = dot2(v2.w, hc.w, a12);
      a03 = dot2(v3.x, ha.x, a03); a03 = dot2(v3.y, ha.y, a03);
      a03 = dot2(v3.z, ha.z, a03); a03 = dot2(v3.w, ha.w, a03);
      a13 = dot2(v3.x, hc.x, a13); a13 = dot2(v3.y, hc.y, a13);
      a13 = dot2(v3.z, hc.z, a13); a13 = dot2(v3.w, hc.w, a13);
    }
    // combine K-halves (both lanes end with identical full sums)
    float gi0 = a00 + __shfl_xor(a00, 1) + x00;
    float gf0 = a01 + __shfl_xor(a01, 1) + x01;
    float gg0 = a02 + __shfl_xor(a02, 1) + x02;
    float go0 = a03 + __shfl_xor(a03, 1) + x03;
    float gi1 = a10 + __shfl_xor(a10, 1) + x10;
    float gf1 = a11 + __shfl_xor(a11, 1) + x11;
    float gg1 = a12 + __shfl_xor(a12, 1) + x12;
    float go1 = a13 + __shfl_xor(a13, 1) + x13;
    c0 = sigm(gf0) * c0 + sigm(gi0) * fast_tanh(gg0);
    c1 = sigm(gf1) * c1 + sigm(gi1) * fast_tanh(gg1);
    float hv0 = sigm(go0) * fast_tanh(c0);
    float hv1 = sigm(go1) * fast_tanh(c1);
    if (!half) {
      hout[(size_t)(bm0 + t) * H_ + u] = hv0;
      hout[(size_t)(bm1 + t) * H_ + u] = hv1;
      hbuf[(cur ^ 1) * 256 + u] = f16bits(hv0);
      hbuf[512 + (cur ^ 1) * 256 + u] = f16bits(hv1);
    }
    __syncthreads();
  }
}

// =====================================================================
// K4: masked attention pooling + logits. One block per batch.
// =====================================================================
__global__ __launch_bounds__(256) void k4_attn(
    const int* __restrict__ lengths, const void* __restrict__ attn_w,
    const void* __restrict__ attn_b, const void* __restrict__ out_w,
    const void* __restrict__ out_b, const char* __restrict__ ws,
    void* __restrict__ out)
{
  __shared__ float aw[256];
  __shared__ float sc[128];
  __shared__ float at[256];
  __shared__ float red[256];

  const int tid = threadIdx.x;
  const int b = blockIdx.x;
  const int f32 = *(const int*)(ws + OFF_FLAG);
  const float* hout = (const float*)(ws + OFF_HOUT);
  const int bm = b * S_;

  aw[tid] = ldv(attn_w, tid, f32);
  __syncthreads();
  if (tid < 128) {
    const float* hp = hout + (size_t)(bm + tid) * H_;
    float acc = 0.f;
    for (int k = 0; k < 256; k += 4) {
      float4 h4 = *(const float4*)(hp + k);
      acc += h4.x * aw[k] + h4.y * aw[k + 1] + h4.z * aw[k + 2] + h4.w * aw[k + 3];
    }
    sc[tid] = acc + ldv(attn_b, 0, f32);
  }
  __syncthreads();
  if (tid == 0) {
    int len = lengths[b];
    float mx = -3.4e38f;
    for (int s = 0; s < len; ++s) mx = fmaxf(mx, sc[s]);
    float sum = 0.f;
    for (int s = 0; s < 128; ++s) {
      float v = (s < len) ? __expf(sc[s] - mx) : 0.f;
      sc[s] = v; sum += v;
    }
    float inv = 1.f / sum;
    for (int s = 0; s < 128; ++s) sc[s] *= inv;
  }
  __syncthreads();
  {
    float acc = 0.f;
    for (int s = 0; s < 128; ++s)
      acc += sc[s] * hout[(size_t)(bm + s) * H_ + tid];
    at[tid] = acc;
  }
  __syncthreads();
  for (int cc = 0; cc < 3; ++cc) {
    red[tid] = at[tid] * ldv(out_w, cc * 256 + tid, f32);
    __syncthreads();
    for (int off = 128; off > 0; off >>= 1) {
      if (tid < off) red[tid] += red[tid + off];
      __syncthreads();
    }
    if (tid == 0) {
      float v = red[0] + ldv(out_b, cc, f32);
      if (f32) ((float*)out)[b * 3 + cc] = v;
      else     ((ushort_t*)out)[b * 3 + cc] = f2b(v);
    }
    __syncthreads();
  }
}

// =====================================================================
extern "C" void kernel_launch(void* const* d_in, const int* in_sizes, int n_in,
                              void* d_out, int out_size, void* d_ws, size_t ws_size,
                              hipStream_t stream)
{
  const int* inputs  = (const int*)d_in[0];
  const int* triples = (const int*)d_in[2];
  const int* lengths = (const int*)d_in[3];
  const int* id2     = (const int*)d_in[4];
  const void* emb    = d_in[5];
  const void* ent    = d_in[6];
  const void* rel    = d_in[7];
  const void* W_ent  = d_in[8];
  const void* W_ih   = d_in[9];
  const void* W_hh   = d_in[10];
  const void* b_lstm = d_in[11];
  const void* attn_w = d_in[12];
  const void* attn_b = d_in[13];
  const void* out_w  = d_in[14];
  const void* out_b  = d_in[15];
  char* ws = (char*)d_ws;

  constexpr int K3_SMEM = 16 * 512 * 16 + 4 * 256 * 2;  // 133120 B
  static bool attr_set = false;
  if (!attr_set) {
    (void)hipFuncSetAttribute((const void*)k3_lstm,
                              hipFuncAttributeMaxDynamicSharedMemorySize, K3_SMEM);
    attr_set = true;
  }

  k_detect<<<dim3(1), dim3(64), 0, stream>>>((const uint_t*)emb, ws);
  k0_prep<<<dim3(2639), dim3(256), 0, stream>>>(W_ent, W_ih, W_hh, ws);
  k1_graph<<<dim3(M_ / 4), dim3(512), 0, stream>>>(inputs, triples, id2, emb, ent, rel, ws);
  k2_xg<<<dim3(64, 8), dim3(256), 0, stream>>>(b_lstm, ws);
  k3_lstm<<<dim3(B_ / 2), dim3(512), K3_SMEM, stream>>>(ws);
  k4_attn<<<dim3(B_), dim3(256), 0, stream>>>(lengths, attn_w, attn_b, out_w, out_b, ws, d_out);
}